// Round 4
// baseline (70.218 us; speedup 1.0000x reference)
//
#include <hip/hip_runtime.h>
#include <hip/hip_bf16.h>
#include <math.h>

// Problem: x[N=16,T=128,V=64,F=16] fp32, a[F=16] fp32.
// score[n,i,j] = (1/T) * sum_t sum_f a[f]*|x[n,t,i,f]-x[n,t,j,f]|
// e = exp(relu(score)); out[n,i,j] = e[n,i,j] / sum_i e[n,i,j]   (column norm)
//
// NOTE (R3 post-mortem): measured floor includes ~42 us harness d_ws poison
// fill + ~2.5 us input restore. Kernel budget is what we optimize.
// Key HW fact learned: uniform-address ds_read_b128 costs FULL b128
// throughput on the per-CU DS pipe -> B operand must NOT come from LDS.
// Here: A via LDS transpose (coalesced stage + conflict-free b128 reads),
// B via wave-uniform GLOBAL loads (1-line L1 broadcast / scalar path, VMEM).

#define Nn 16
#define Tt 128
#define Vv 64
#define Ff 16
#define CHUNKS 16   // T split into 16 chunks of 8
#define TC 8
#define JSPLIT 4    // j split into 4 groups of 16 per block
#define JPW 4       // j's per wave (4 waves x 4 j = 16 j per block)
#define PITCH 20    // LDS row pitch: 80 B -> 16B-superbank stride 5 mod 8
                    // -> all 8 superbanks hit uniformly by b128 reads

// ---------------- Kernel 1: partial weighted-L1 scores per t-chunk ----------
// grid = (CHUNKS, Nn, JSPLIT) = 1024 blocks, block 256, LDS 40 KB
// -> 4 blocks/CU (160 KB), 4 waves/SIMD.
// ws layout: [n][c][j][i] fp32 (4 MB).
__global__ __launch_bounds__(256, 4) void gls_scores(const float* __restrict__ x,
                                                     const float* __restrict__ a,
                                                     float* __restrict__ ws) {
    __shared__ float xs[TC * Vv * PITCH];   // 8*64*20*4 = 40 KB

    const int c   = blockIdx.x;
    const int n   = blockIdx.y;
    const int z   = blockIdx.z;
    const int tid = threadIdx.x;
    const int i   = tid & 63;
    const int w   = __builtin_amdgcn_readfirstlane(tid >> 6);
    const int j0  = z * (Vv / JSPLIT) + w * JPW;   // wave-uniform

    // ---- stage x[n, c*8 .. c*8+7, :, :]: 8192 floats = 2048 float4,
    //      8 per thread, lane-contiguous -> perfectly coalesced ----
    const float* xnc = x + (size_t)(n * Tt + c * TC) * (Vv * Ff);
    const float4* xg = (const float4*)xnc;
#pragma unroll
    for (int k = 0; k < 8; ++k) {
        const int f4  = tid + k * 256;
        const float4 val = xg[f4];
        const int tl  = f4 >> 8;            // /256 float4s per t-slice
        const int v   = (f4 >> 2) & 63;
        const int f   = (f4 & 3) << 2;
        *(float4*)&xs[(tl * Vv + v) * PITCH + f] = val;
    }

    float af[Ff];
#pragma unroll
    for (int f = 0; f < Ff; ++f) af[f] = a[f];   // uniform -> SGPRs

    __syncthreads();

    float acc[JPW] = {0.f, 0.f, 0.f, 0.f};

#pragma unroll 2
    for (int tt = 0; tt < TC; ++tt) {
        // A: lane i's 16 features from LDS (conflict-free b128 x4)
        const float* xi = &xs[(tt * Vv + i) * PITCH];
        const float4 A0 = *(const float4*)(xi);
        const float4 A1 = *(const float4*)(xi + 4);
        const float4 A2 = *(const float4*)(xi + 8);
        const float4 A3 = *(const float4*)(xi + 12);
        // B: wave-uniform GLOBAL address -> 1-line lookup, L1 broadcast
        const float* xtg = xnc + tt * (Vv * Ff);
#pragma unroll
        for (int jj = 0; jj < JPW; ++jj) {
            const float* xb = xtg + (j0 + jj) * Ff;
            const float4 B0 = *(const float4*)(xb + 0);
            const float4 B1 = *(const float4*)(xb + 4);
            const float4 B2 = *(const float4*)(xb + 8);
            const float4 B3 = *(const float4*)(xb + 12);
            float s = acc[jj];
            s = fmaf(fabsf(A0.x - B0.x), af[0],  s);
            s = fmaf(fabsf(A0.y - B0.y), af[1],  s);
            s = fmaf(fabsf(A0.z - B0.z), af[2],  s);
            s = fmaf(fabsf(A0.w - B0.w), af[3],  s);
            s = fmaf(fabsf(A1.x - B1.x), af[4],  s);
            s = fmaf(fabsf(A1.y - B1.y), af[5],  s);
            s = fmaf(fabsf(A1.z - B1.z), af[6],  s);
            s = fmaf(fabsf(A1.w - B1.w), af[7],  s);
            s = fmaf(fabsf(A2.x - B2.x), af[8],  s);
            s = fmaf(fabsf(A2.y - B2.y), af[9],  s);
            s = fmaf(fabsf(A2.z - B2.z), af[10], s);
            s = fmaf(fabsf(A2.w - B2.w), af[11], s);
            s = fmaf(fabsf(A3.x - B3.x), af[12], s);
            s = fmaf(fabsf(A3.y - B3.y), af[13], s);
            s = fmaf(fabsf(A3.z - B3.z), af[14], s);
            s = fmaf(fabsf(A3.w - B3.w), af[15], s);
            acc[jj] = s;
        }
    }

    // ws[n][c][j][i] — lane-i contiguous => coalesced 256B stores
    float* wsb = ws + (((size_t)n * CHUNKS + c) * Vv + j0) * Vv;
#pragma unroll
    for (int jj = 0; jj < JPW; ++jj)
        wsb[jj * Vv + i] = acc[jj];
}

// ---------------- Kernel 2: chunk-reduce + exp(relu) + column-normalize -----
// grid = (Nn, 16) = 256 blocks, block 256 (4 waves). One (n,j) column per wave.
__global__ __launch_bounds__(256) void gls_norm(const float* __restrict__ ws,
                                                float* __restrict__ out) {
    const int n   = blockIdx.x;
    const int jq  = blockIdx.y;
    const int tid = threadIdx.x;
    const int i   = tid & 63;            // lane == row index i (reduction axis)
    const int w   = tid >> 6;
    const int j   = jq * 4 + w;          // this wave's column

    const float* wsn = ws + (size_t)n * CHUNKS * (Vv * Vv);
    float s = 0.f;
#pragma unroll
    for (int cc = 0; cc < CHUNKS; ++cc)
        s += wsn[(cc * Vv + j) * Vv + i];     // lane-coalesced 256B loads

    const float e = expf(fmaxf(s * (1.0f / (float)Tt), 0.0f));
    float tsum = e;
#pragma unroll
    for (int m = 1; m < 64; m <<= 1) tsum += __shfl_xor(tsum, m, 64);

    out[((size_t)n * Vv + i) * Vv + j] = e / tsum;
}

extern "C" void kernel_launch(void* const* d_in, const int* in_sizes, int n_in,
                              void* d_out, int out_size, void* d_ws, size_t ws_size,
                              hipStream_t stream) {
    const float* x = (const float*)d_in[0];   // [16,128,64,16]
    const float* a = (const float*)d_in[1];   // [16,1]
    float* out = (float*)d_out;               // [16,64,64]
    float* ws  = (float*)d_ws;                // 16*16*64*64*4 = 4 MB used

    dim3 g1(CHUNKS, Nn, JSPLIT);
    gls_scores<<<g1, 256, 0, stream>>>(x, a, ws);
    dim3 g2(Nn, 16);
    gls_norm<<<g2, 256, 0, stream>>>(ws, out);
}